// Round 2
// baseline (341.188 us; speedup 1.0000x reference)
//
#include <hip/hip_runtime.h>
#include <cstdint>
#include <cstddef>

// Problem constants
#define NROWS   16384
#define L1DIM   3072
#define NEXP    8
#define NO1     16        // L2+1 outputs of layer 1
#define NFEAT   30        // 2*15 features into layer 2
#define NL3     32
#define RFEAT   32        // ROUTER_FEATS

// Main-kernel tiling
#define RPB     32        // rows per block (32 -> 520 blocks ~= 2 blocks/CU for overlap)
#define KC      192       // K chunk
#define NCHUNK  16        // 3072/192
#define PITCH   196       // LDS pitch in floats (mult of 4; 196%32=4 rotates banks per row)
#define NKS     8         // k-slices (half-wave each)
#define KSL     24        // K floats per slice (KC/NKS)
#define SENT    0x7FFFFFFF
#define RBLK    256       // router/scatter grid (16384/64)
#define MAXSLOTS (NROWS + NEXP*RPB)   // 16640
#define MBLK    (MAXSLOTS/RPB)        // 520

// Device-static scratch: fully rewritten before every read on each call,
// so harness poisoning of d_ws is irrelevant (d_ws unused).
__device__ int g_eid[NROWS];
__device__ int g_bc[RBLK*NEXP];
__device__ int g_off[NEXP+1];
__device__ int g_cur[NEXP];
__device__ int g_bucket[MAXSLOTS];

// ---------------- K1: router + per-block histogram (64 thr/block, 256 blocks) ----
__global__ __launch_bounds__(64) void k_router(const float* __restrict__ x,
                                               const float* __restrict__ rw,
                                               const float* __restrict__ rb){
  int tid = threadIdx.x;
  int row = blockIdx.x*64 + tid;
  const float* xr = x + (size_t)row * L1DIM;
  float rin[2*RFEAT];
  #pragma unroll
  for (int i=0;i<8;i++){
    float4 v = *(const float4*)(xr + i*4);
    rin[i*4+0]=v.x; rin[i*4+1]=v.y; rin[i*4+2]=v.z; rin[i*4+3]=v.w;
  }
  #pragma unroll
  for (int i=0;i<8;i++){
    float4 v = *(const float4*)(xr + (L1DIM/2) + i*4);
    rin[32+i*4+0]=v.x; rin[32+i*4+1]=v.y; rin[32+i*4+2]=v.z; rin[32+i*4+3]=v.w;
  }
  float best = -3.0e38f; int be = 0;
  #pragma unroll
  for (int e=0;e<NEXP;e++){
    float s = rb[e];
    #pragma unroll
    for (int i=0;i<64;i++) s += rin[i]*rw[e*64+i];
    if (s > best){ best = s; be = e; }   // strict > keeps first max (jnp.argmax)
  }
  g_eid[row] = be;
  __shared__ int cnt[NEXP];
  if (tid < NEXP) cnt[tid] = 0;
  __syncthreads();
  atomicAdd(&cnt[be], 1);
  __syncthreads();
  if (tid < NEXP) g_bc[blockIdx.x*NEXP + tid] = cnt[tid];
}

// ---------------- K2: counts -> padded offsets, zero cursors, sentinel-fill padding ----
__global__ __launch_bounds__(256) void k_offsets(){
  __shared__ int part[256];
  __shared__ int scnt[NEXP];
  __shared__ int soff[NEXP+1];
  int tid = threadIdx.x;
  // parallel histogram reduction: expert = tid&7, block-group = tid>>3 (32 groups)
  {
    int e = tid & 7, grp = tid >> 3;
    int s = 0;
    for (int b = grp; b < RBLK; b += 32) s += g_bc[b*NEXP + e];
    part[tid] = s;
  }
  __syncthreads();
  if (tid < NEXP){
    int t = 0;
    #pragma unroll
    for (int g=0; g<32; g++) t += part[g*NEXP + tid];
    scnt[tid] = t;
    g_cur[tid] = 0;
  }
  __syncthreads();
  if (tid == 0){
    int o = 0;
    for (int ee=0; ee<NEXP; ee++){
      soff[ee] = o;
      o += ((scnt[ee] + RPB - 1) / RPB) * RPB;
    }
    soff[NEXP] = o;
    for (int i=0;i<=NEXP;i++) g_off[i] = soff[i];
  }
  __syncthreads();
  for (int ee=0; ee<NEXP; ee++){
    int s    = soff[ee] + scnt[ee];
    int epad = soff[ee+1];
    for (int i = s + tid; i < epad; i += 256) g_bucket[i] = SENT;
  }
}

// ---------------- K3: scatter rows into buckets (one wave/block, aggregated atomics) ----
__global__ __launch_bounds__(64) void k_scatter(){
  int lane = threadIdx.x;           // blockDim = 64 -> lane == tid
  int row = blockIdx.x*64 + lane;
  int e = g_eid[row];
  unsigned long long peers = 0;
  #pragma unroll
  for (int j=0;j<NEXP;j++){
    unsigned long long m = __ballot(e == j);
    if (e == j) peers = m;
  }
  int rank   = __popcll(peers & ((1ull << lane) - 1ull));
  int leader = __ffsll((unsigned long long)peers) - 1;
  int base = 0;
  if (lane == leader) base = atomicAdd(&g_cur[e], __popcll(peers));
  base = __shfl(base, leader, 64);
  g_bucket[g_off[e] + base + rank] = row;
}

// ---------------- K4: expert-uniform 32-row GEMM (3072 -> 16) + fused MLP epilogue ----
__global__ __launch_bounds__(256,2) void k_main(const float* __restrict__ x,
    const float* __restrict__ l1w, const float* __restrict__ l1b,
    const float* __restrict__ l2w, const float* __restrict__ l2b,
    const float* __restrict__ ow,  const float* __restrict__ ob,
    float* __restrict__ out){
  __shared__ __align__(16) float sX[RPB][PITCH];   // 25088 B
  __shared__ __align__(16) float sW[NO1][PITCH];   // 12544 B
  __shared__ int sRows[RPB];
  __shared__ int sE;

  int tid = threadIdx.x;
  int slot0 = blockIdx.x * RPB;
  if (tid == 0){
    int e = -1;
    if (slot0 < g_off[NEXP]){
      #pragma unroll
      for (int j=0;j<NEXP;j++) if (slot0 >= g_off[j] && slot0 < g_off[j+1]) e = j;
    }
    sE = e;
  }
  __syncthreads();
  int e = sE;
  if (e < 0) return;
  if (tid < RPB) sRows[tid] = g_bucket[slot0 + tid];

  int ks = tid >> 5;       // k-slice 0..7 (half-wave each)
  int l5 = tid & 31;
  int og = l5 & 3;         // outs og, og+4, og+8, og+12
  int rg = l5 >> 2;        // rows rg, rg+8, rg+16, rg+24

  float acc[4][4];
  #pragma unroll
  for (int i=0;i<4;i++)
    #pragma unroll
    for (int j=0;j<4;j++) acc[i][j] = 0.f;

  const float* we = l1w + (size_t)e * (NO1 * L1DIM);

  for (int c=0;c<NCHUNK;c++){
    int kb = c * KC;
    __syncthreads();
    // stage X tile: 32 rows x 48 float4 (coalesced 768-B runs per row)
    #pragma unroll
    for (int p=0;p<6;p++){
      int i = tid + p*256;
      int r = i / (KC/4), k4 = i % (KC/4);
      int gr = sRows[r];
      if (gr == SENT) gr = 0;
      float4 v = *(const float4*)(x + (size_t)gr * L1DIM + kb + k4*4);
      *(float4*)(&sX[r][k4*4]) = v;
    }
    // stage W tile: 16 x 48 float4
    #pragma unroll
    for (int p=0;p<3;p++){
      int i = tid + p*256;
      int o = i / (KC/4), k4 = i % (KC/4);
      float4 v = *(const float4*)(we + (size_t)o * L1DIM + kb + k4*4);
      *(float4*)(&sW[o][k4*4]) = v;
    }
    __syncthreads();
    int k0 = ks * KSL;
    #pragma unroll
    for (int q=0;q<KSL/4;q++){
      int k = k0 + q*4;
      float4 xv[4], wv[4];
      #pragma unroll
      for (int i=0;i<4;i++) xv[i] = *(const float4*)(&sX[rg + i*8][k]);
      #pragma unroll
      for (int j=0;j<4;j++) wv[j] = *(const float4*)(&sW[og + j*4][k]);
      #pragma unroll
      for (int ri=0;ri<4;ri++)
        #pragma unroll
        for (int oi=0;oi<4;oi++){
          acc[ri][oi] += xv[ri].x * wv[oi].x;
          acc[ri][oi] += xv[ri].y * wv[oi].y;
          acc[ri][oi] += xv[ri].z * wv[oi].z;
          acc[ri][oi] += xv[ri].w * wv[oi].w;
        }
    }
  }

  // cross-k-slice reduction through LDS (reuse sX area; [8][32][17] floats = 4352)
  __syncthreads();
  float* red = &sX[0][0];
  #pragma unroll
  for (int ri=0;ri<4;ri++)
    #pragma unroll
    for (int oi=0;oi<4;oi++)
      red[(ks*RPB + (rg + ri*8))*17 + (og + oi*4)] = acc[ri][oi];
  __syncthreads();

  // fused epilogue: 4 threads per row, 8 layer-2 outs each (tid < 128 active)
  if (tid < RPB*4){
    int row = tid >> 2;
    int g   = tid & 3;
    float l1c[NO1];
    #pragma unroll
    for (int j=0;j<NO1;j++){
      float s = l1b[e*NO1 + j];
      #pragma unroll
      for (int sl=0;sl<NKS;sl++) s += red[(sl*RPB + row)*17 + j];
      l1c[j] = s;
    }
    float feat[NFEAT];
    #pragma unroll
    for (int j=0;j<15;j++){
      float v = l1c[j];
      feat[j]    = fminf(v*v*(255.0f/256.0f), 1.0f);   // square >= 0 already
      feat[15+j] = fminf(fmaxf(v, 0.0f), 1.0f);
    }
    float l1xout = l1c[15];
    const float* w2 = l2w + e*NL3*NFEAT;
    const float* wo = ow  + e*NL3;
    float acc3 = 0.f;
    #pragma unroll
    for (int oo=0;oo<8;oo++){
      int o = g*8 + oo;
      float s = l2b[e*NL3 + o];
      #pragma unroll
      for (int i=0;i<NFEAT;i++) s += feat[i]*w2[o*NFEAT + i];
      s = fminf(fmaxf(s, 0.0f), 1.0f);
      acc3 += s * wo[o];
    }
    acc3 += __shfl_xor(acc3, 1);
    acc3 += __shfl_xor(acc3, 2);
    if (g == 0){
      int grow = sRows[row];
      if (grow != SENT) out[grow] = acc3 + ob[e] + l1xout;
    }
  }
}

extern "C" void kernel_launch(void* const* d_in, const int* in_sizes, int n_in,
                              void* d_out, int out_size, void* d_ws, size_t ws_size,
                              hipStream_t stream){
  (void)in_sizes; (void)n_in; (void)d_ws; (void)ws_size; (void)out_size;
  const float* x   = (const float*)d_in[0];
  const float* rw  = (const float*)d_in[1];
  const float* rb  = (const float*)d_in[2];
  const float* l1w = (const float*)d_in[3];
  const float* l1b = (const float*)d_in[4];
  const float* l2w = (const float*)d_in[5];
  const float* l2b = (const float*)d_in[6];
  const float* ow  = (const float*)d_in[7];
  const float* ob  = (const float*)d_in[8];
  float* out = (float*)d_out;

  hipLaunchKernelGGL(k_router,  dim3(RBLK), dim3(64),  0, stream, x, rw, rb);
  hipLaunchKernelGGL(k_offsets, dim3(1),    dim3(256), 0, stream);
  hipLaunchKernelGGL(k_scatter, dim3(RBLK), dim3(64),  0, stream);
  hipLaunchKernelGGL(k_main,    dim3(MBLK), dim3(256), 0, stream,
                     x, l1w, l1b, l2w, l2b, ow, ob, out);
}